// Round 4
// baseline (92.492 us; speedup 1.0000x reference)
//
#include <hip/hip_runtime.h>

#define B_ 96
#define S_ 128
#define C_ 141
#define D_ 768
#define K_ 1536   // 2*D
#define M_ (B_*S_)   // 12288 (worst case)
#define N_ 1536   // 2*D

typedef unsigned short u16;
typedef __bf16 bf16x8 __attribute__((ext_vector_type(8)));
typedef float f32x4 __attribute__((ext_vector_type(4)));

__device__ __forceinline__ u16 f2bf(float x) {
  unsigned int u = __float_as_uint(x);
  u = u + 0x7fffu + ((u >> 16) & 1u);   // RNE
  return (u16)(u >> 16);
}

__device__ __forceinline__ void gload_lds16(const void* g, void* l) {
  __builtin_amdgcn_global_load_lds(
      (const __attribute__((address_space(1))) unsigned int*)g,
      (__attribute__((address_space(3))) unsigned int*)l, 16, 0, 0);
}

// ---- tokmap + per-batch used-token rank (one block per batch, 192 thr) ----
__global__ void tokmap_rank_kernel(const int* __restrict__ om,
                                   int* __restrict__ tokmap,
                                   int* __restrict__ cidx,
                                   int* __restrict__ cnt) {
  __shared__ int st[C_];
  __shared__ int c0;
  const int b = blockIdx.x;
  const int t = threadIdx.x;   // 0..191
  int s = 0, e = 0;
  if (t < S_) {
    s = om[(b * S_ + t) * 2 + 0];
    e = om[(b * S_ + t) * 2 + 1];
  }
  if (t < C_) st[t] = -1;
  __syncthreads();
  if (t < S_) {
    for (int c = s; c < e; ++c) st[c] = t;   // disjoint -> race-free
  }
  __syncthreads();
  if (t < C_) tokmap[b * C_ + t] = st[t];

  bool used = (t < S_) && (s < e);
  unsigned long long mset = __ballot(used);
  int lane = t & 63;
  int r = __popcll(mset & ((1ull << lane) - 1ull));
  int wcnt = __popcll(mset);
  if (t == 0) c0 = wcnt;
  __syncthreads();
  int rank = r + ((t >> 6) == 1 ? c0 : 0);
  if (t < S_) cidx[b * S_ + t] = used ? rank : -1;
  if (t == 64) cnt[b] = c0 + wcnt;
}

// ---- exclusive scan of 96 batch counts ----
__global__ void scan_kernel(const int* __restrict__ cnt, int* __restrict__ boff,
                            int* __restrict__ mc) {
  __shared__ int sc[B_];
  int t = threadIdx.x;   // 128
  if (t < B_) sc[t] = cnt[t];
  __syncthreads();
  if (t == 0) {
    int acc = 0;
    for (int i = 0; i < B_; ++i) { int v = sc[i]; sc[i] = acc; acc += v; }
    mc[0] = acc;                    // Mc: total used rows
    mc[1] = (acc + 127) >> 7;       // number of 128-row m-tiles
  }
  __syncthreads();
  if (t < B_) boff[t] = sc[t];
}

// ---- pack: compact used rows of concat(h0,h1) -> bf16 A; W -> bf16 ----
__global__ void pack_kernel(const float* __restrict__ h0,
                            const float* __restrict__ h1,
                            const float* __restrict__ W,
                            const int* __restrict__ boff,
                            const int* __restrict__ cidx,
                            u16* __restrict__ Ap, u16* __restrict__ Wp,
                            int* __restrict__ rowinfo) {
  const int blk = blockIdx.x;
  const int t = threadIdx.x;      // 0..191
  if (blk < B_ * S_) {
    const int i = blk;            // b*S + tok
    int r = cidx[i];
    if (r < 0) return;
    const int b = i >> 7;
    const int dst = boff[b] + r;
    if (t == 0) rowinfo[dst] = i;
    const float4* src = (t < 96)
        ? ((const float4*)(h0 + (size_t)i * D_)) + 2 * t
        : ((const float4*)(h1 + (size_t)i * D_)) + 2 * (t - 96);
    float4 v0 = src[0], v1 = src[1];
    ushort4 o0, o1;
    o0.x = f2bf(v0.x); o0.y = f2bf(v0.y); o0.z = f2bf(v0.z); o0.w = f2bf(v0.w);
    o1.x = f2bf(v1.x); o1.y = f2bf(v1.y); o1.z = f2bf(v1.z); o1.w = f2bf(v1.w);
    ushort4* dp = (ushort4*)(Ap + (size_t)dst * K_ + 8 * t);
    dp[0] = o0; dp[1] = o1;
  } else {
    int idx = (blk - B_ * S_) * 192 + t;   // f4 index into W (total 589824)
    float4 v = ((const float4*)W)[idx];
    ushort4 o;
    o.x = f2bf(v.x); o.y = f2bf(v.y); o.z = f2bf(v.z); o.w = f2bf(v.w);
    ((ushort4*)Wp)[idx] = o;
  }
}

// ---- zero-fill uncovered (b,c) output rows ----
__global__ void zerofill_kernel(const int* __restrict__ tokmap,
                                float* __restrict__ out) {
  int bc = blockIdx.x;
  if (tokmap[bc] >= 0) return;
  int t = threadIdx.x;   // 192
  float4 z = {0.f, 0.f, 0.f, 0.f};
  float4* o4 = (float4*)out;
  size_t base = (size_t)bc * 192;              // 192 f4 per (b,c) row
  size_t half4 = (size_t)B_ * C_ * 192;
  o4[base + t] = z;
  o4[half4 + base + t] = z;
}

// ---- GEMM + fused scatter epilogue ----
// 2-deep triple-buffered K-loop (1 barrier/iter), LDS-transpose epilogue.
__global__ void __launch_bounds__(256) gemm_kernel(
    const u16* __restrict__ A, const u16* __restrict__ Wt,
    const float* __restrict__ bias, const int* __restrict__ mc,
    const int* __restrict__ rowinfo, const int* __restrict__ om,
    float* __restrict__ out) {
  // runtime-balanced XCD-chunked swizzle
  const int id = blockIdx.y * 12 + blockIdx.x;   // 0..1151
  const int active = mc[1] * 12;
  const int cpx = (active + 7) >> 3;
  const int xcd = id & 7, slot = id >> 3;
  if (slot >= cpx) return;
  const int w = xcd * cpx + slot;
  if (w >= active) return;
  const int mtile = w / 12, ntile = w - mtile * 12;
  const int n0 = ntile * 128;
  const int m0 = mtile * 128;

  // 3 buffers x (A 8KB + B 8KB) = 48 KB; epilogue transpose reuses base
  __shared__ char smem[49152];
  const int t = threadIdx.x;
  const int lane = t & 63;
  const int wid = t >> 6;
  const int wm = wid >> 1;
  const int wn = wid & 1;
  const int lr = lane & 15;
  const int lk = lane >> 4;

  f32x4 acc[4][4];
#pragma unroll
  for (int i = 0; i < 4; ++i)
#pragma unroll
    for (int j = 0; j < 4; ++j) acc[i][j] = (f32x4){0.f, 0.f, 0.f, 0.f};

  const int rowc = t >> 2;
  const int koff = (t & 3) * 8;
  const u16* pa0 = A + (size_t)(m0 + rowc) * K_ + koff;
  const u16* pa1 = A + (size_t)(m0 + 64 + rowc) * K_ + koff;
  const u16* pb0 = Wt + (size_t)(n0 + rowc) * K_ + koff;
  const u16* pb1 = Wt + (size_t)(n0 + 64 + rowc) * K_ + koff;
  const int l0 = wid * 1024;   // wave-uniform LDS byte base within 4KB stripe

#define STAGE(buf, kk) do {                                   \
    char* ab_ = smem + (buf) * 16384;                         \
    gload_lds16(pa0 + (kk), ab_ + l0);                        \
    gload_lds16(pa1 + (kk), ab_ + 4096 + l0);                 \
    gload_lds16(pb0 + (kk), ab_ + 8192 + l0);                 \
    gload_lds16(pb1 + (kk), ab_ + 12288 + l0);                \
  } while (0)

  STAGE(0, 0);
  STAGE(1, 32);
  int cur = 0;
  for (int kk = 0; kk < K_; kk += 32) {
    __syncthreads();            // implicit vmcnt(0): buf[cur] ready; prev reads done
    if (kk + 64 < K_) {
      int nb = cur + 2; if (nb >= 3) nb -= 3;
      STAGE(nb, kk + 64);       // 2-ahead, in flight across this compute phase
    }
    const char* ab = smem + cur * 16384;
    bf16x8 af[4], bfr[4];
#pragma unroll
    for (int mt = 0; mt < 4; ++mt)
      af[mt] = *(const bf16x8*)(ab + (wm * 64 + mt * 16 + lr) * 64 + lk * 16);
#pragma unroll
    for (int nt = 0; nt < 4; ++nt)
      bfr[nt] = *(const bf16x8*)(ab + 8192 + (wn * 64 + nt * 16 + lr) * 64 + lk * 16);
#pragma unroll
    for (int mt = 0; mt < 4; ++mt)
#pragma unroll
      for (int nt = 0; nt < 4; ++nt)
        acc[mt][nt] = __builtin_amdgcn_mfma_f32_16x16x32_bf16(
            af[mt], bfr[nt], acc[mt][nt], 0, 0, 0);
    cur += 1; if (cur == 3) cur = 0;
  }
#undef STAGE

  // ---- epilogue: LDS transpose (32 rows x 132 f32, +4 pad) + wide scatter ----
  const int Mc = mc[0];
  const size_t half = (size_t)B_ * C_ * D_;
  const size_t colbase = (n0 < D_) ? (size_t)n0 : (size_t)(n0 - D_) + half;
  float bn[4];
#pragma unroll
  for (int nt = 0; nt < 4; ++nt) bn[nt] = bias[n0 + wn * 64 + nt * 16 + lr];

  float* tb = (float*)smem;           // 32*132*4 = 16896 B
  const int rrow = t >> 3;            // 0..31
  const int rcol = (t & 7) * 16;      // 0,16,..,112
  const int gmbase = m0 + (rrow >> 4) * 64 + (rrow & 15);

#pragma unroll
  for (int mt = 0; mt < 4; ++mt) {
    __syncthreads();                  // K-loop done / prev mt reads done
#pragma unroll
    for (int nt = 0; nt < 4; ++nt)
#pragma unroll
      for (int r = 0; r < 4; ++r)
        tb[(wm * 16 + lk * 4 + r) * 132 + wn * 64 + nt * 16 + lr] =
            acc[mt][nt][r] + bn[nt];
    __syncthreads();
    int gm = gmbase + mt * 16;
    if (gm < Mc) {
      int i = rowinfo[gm];
      int bb = i >> 7;                // / S_
      int s = om[2 * i], e = om[2 * i + 1];
      const float* src = tb + rrow * 132 + rcol;
      float4 v0 = *(const float4*)(src);
      float4 v1 = *(const float4*)(src + 4);
      float4 v2 = *(const float4*)(src + 8);
      float4 v3 = *(const float4*)(src + 12);
      for (int c = s; c < e; ++c) {
        float* dst = out + (size_t)(bb * C_ + c) * D_ + colbase + rcol;
        ((float4*)dst)[0] = v0;
        ((float4*)dst)[1] = v1;
        ((float4*)dst)[2] = v2;
        ((float4*)dst)[3] = v3;
      }
    }
  }
}

extern "C" void kernel_launch(void* const* d_in, const int* in_sizes, int n_in,
                              void* d_out, int out_size, void* d_ws, size_t ws_size,
                              hipStream_t stream) {
  (void)in_sizes; (void)n_in; (void)out_size; (void)ws_size;
  const float* h0 = (const float*)d_in[0];
  const float* h1 = (const float*)d_in[1];
  const float* W  = (const float*)d_in[2];
  const float* bias = (const float*)d_in[3];
  const int* om = (const int*)d_in[4];

  char* ws = (char*)d_ws;
  u16* Ap = (u16*)(ws);                   // 37,748,736 B (worst case)
  u16* Wp = (u16*)(ws + 37748736);        //  4,718,592 B
  int* rowinfo = (int*)(ws + 42467328);   //     49,152 B
  int* tokmap  = (int*)(ws + 42516480);   //     54,144 B
  int* cidx    = (int*)(ws + 42570624);   //     49,152 B
  int* cnt     = (int*)(ws + 42619776);   //        384 B
  int* boff    = (int*)(ws + 42620160);   //        384 B
  int* mc      = (int*)(ws + 42620544);   //         16 B
  float* out = (float*)d_out;

  tokmap_rank_kernel<<<B_, 192, 0, stream>>>(om, tokmap, cidx, cnt);
  scan_kernel<<<1, 128, 0, stream>>>(cnt, boff, mc);
  pack_kernel<<<B_ * S_ + 3072, 192, 0, stream>>>(h0, h1, W, boff, cidx,
                                                  Ap, Wp, rowinfo);
  zerofill_kernel<<<B_ * C_, 192, 0, stream>>>(tokmap, out);
  gemm_kernel<<<dim3(12, 96), 256, 0, stream>>>(Ap, Wp, bias, mc,
                                                rowinfo, om, out);
}